// Round 2
// baseline (113.717 us; speedup 1.0000x reference)
//
#include <hip/hip_runtime.h>
#include <hip/hip_bf16.h>
#include <stdint.h>

#define IN_F   128
#define OUT_F  128
#define NUM_F  8
#define NROWS  (16*4096)

typedef __bf16  bf16x8  __attribute__((ext_vector_type(8)));
typedef float   f32x16  __attribute__((ext_vector_type(16)));

// W_perm: 9 feature-blocks x 8 k-steps x 4 n-tiles x 64 lanes x 8 bf16 = 294912 B
#define WP_CHUNKS (9*8*4*64)
#define WP_BYTES  (WP_CHUNKS*16)
#define BIAS_OFF  WP_BYTES

// ---------------- prep: build permuted bf16 weight + bias ----------------
__global__ __launch_bounds__(256) void skan_prep(
    const float* __restrict__ base_w,   // [OUT_F][IN_F]
    const float* __restrict__ scale,    // [OUT_F]
    const float* __restrict__ coef,     // [GROUPS][1][NUM_F]
    const float* __restrict__ conv_w,   // [NUM_F][OUT_F][IN_F]
    const float* __restrict__ conv_b,   // [NUM_F][OUT_F]
    __bf16* __restrict__ Wp, float* __restrict__ bias)
{
    int gid = blockIdx.x * 256 + threadIdx.x;        // 0..18431 chunk id
    int l  = gid & 63;
    int t  = (gid >> 6) & 3;
    int s  = (gid >> 8) & 7;
    int fb = gid >> 11;                              // 0..8
    int n  = t * 32 + (l & 31);
    int k0 = s * 16 + (l >> 5) * 8;
    __bf16* dst = Wp + (size_t)gid * 8;
    if (fb == 0) {
        #pragma unroll
        for (int j = 0; j < 8; ++j)
            dst[j] = (__bf16)base_w[n * IN_F + k0 + j];
    } else {
        int f = fb - 1;
        float sc = scale[n];
        #pragma unroll
        for (int j = 0; j < 8; ++j) {
            int k = k0 + j;
            float v = conv_w[((size_t)f * OUT_F + n) * IN_F + k]
                      * coef[(k >> 4) * NUM_F + f] * sc;
            dst[j] = (__bf16)v;
        }
    }
    if (gid < OUT_F) {
        float b = 0.f;
        #pragma unroll
        for (int f = 0; f < NUM_F; ++f) b += conv_b[f * OUT_F + gid];
        bias[gid] = b * scale[gid];
    }
}

// ---------------- main fused kernel ----------------
__device__ __forceinline__ void gld_lds16(const void* g, void* l) {
    __builtin_amdgcn_global_load_lds(
        (const __attribute__((address_space(1))) uint32_t*)g,
        (__attribute__((address_space(3))) uint32_t*)l, 16, 0, 0);
}

__global__ __launch_bounds__(256, 2) void skan_main(
    const float* __restrict__ x,        // [NROWS][IN_F]
    const __bf16* __restrict__ Wp,
    const float* __restrict__ bias,
    float* __restrict__ out)            // [NROWS][OUT_F]
{
    // 64 KB: double-buffered W (2 x 32 KB) during the loop,
    // then reused as 4 x 16 KB wave-private transpose scratch in the epilogue.
    __shared__ float smemf[16384];
    char* smem = (char*)smemf;

    const int tid = threadIdx.x;
    const int w   = tid >> 6;           // wave 0..3
    const int l   = tid & 63;
    const int hl  = l & 31;
    const int h   = l >> 5;
    const int m0  = blockIdx.x * 128 + w * 32;   // wave's row base
    const int m   = m0 + hl;                     // this lane's row (A operand)

    // ---- issue stage of fb=0 into buffer 0 immediately (no deps) ----
    {
        const char* src = (const char*)Wp;      // fb 0
        #pragma unroll
        for (int r = 0; r < 8; ++r) {
            int off = (r * 4 + w) * 1024;
            gld_lds16(src + off + l * 16, smem + off);
        }
    }

    // ---- load this lane's 64 x elements in A-fragment order ----
    // element (s,j): col = s*16 + h*8 + j
    const float4* x4 = (const float4*)x + (size_t)m * (IN_F / 4) + 2 * h;
    float xe[64];
    #pragma unroll
    for (int s = 0; s < 8; ++s) {
        float4 a = x4[4 * s];
        float4 b = x4[4 * s + 1];
        xe[8*s+0] = a.x; xe[8*s+1] = a.y; xe[8*s+2] = a.z; xe[8*s+3] = a.w;
        xe[8*s+4] = b.x; xe[8*s+5] = b.y; xe[8*s+6] = b.z; xe[8*s+7] = b.w;
    }

    // ---- A fragments for fb=0 (silu) ----
    bf16x8 af[8];
    #pragma unroll
    for (int s = 0; s < 8; ++s)
        #pragma unroll
        for (int j = 0; j < 8; ++j) {
            float v = xe[8*s+j];
            float sv = v * __builtin_amdgcn_rcpf(1.0f + __expf(-v));
            af[s][j] = (__bf16)sv;
        }

    f32x16 acc[4];
    #pragma unroll
    for (int t = 0; t < 4; ++t)
        #pragma unroll
        for (int r = 0; r < 16; ++r) acc[t][r] = 0.f;

    __syncthreads();   // stage(0) complete (barrier drains vmcnt)

    for (int fb = 0; fb < 9; ++fb) {
        // ---- issue prefetch of fb+1 into the other buffer ----
        if (fb < 8) {
            const char* src = (const char*)Wp + (size_t)(fb + 1) * 32768;
            char* dst = smem + ((fb + 1) & 1) * 32768;
            #pragma unroll
            for (int r = 0; r < 8; ++r) {
                int off = (r * 4 + w) * 1024;
                gld_lds16(src + off + l * 16, dst + off);
            }
        }
        // ---- MFMA on buffer fb&1 (staged last iter, drained at last barrier) ----
        const bf16x8* bp = (const bf16x8*)(smem + (fb & 1) * 32768);
        #pragma unroll
        for (int s = 0; s < 8; ++s) {
            #pragma unroll
            for (int t = 0; t < 4; ++t) {
                bf16x8 b = bp[(s * 4 + t) * 64 + l];
                acc[t] = __builtin_amdgcn_mfma_f32_32x32x16_bf16(af[s], b, acc[t], 0, 0, 0);
            }
        }
        // ---- A fragments for next fb (sin path), overlaps MFMA/loads ----
        if (fb < 8) {
            float cf = (float)(fb + 1) * 0.15915494309189535f;  // f/(2*pi)
            #pragma unroll
            for (int s = 0; s < 8; ++s)
                #pragma unroll
                for (int j = 0; j < 8; ++j) {
                    float a = __builtin_amdgcn_fractf(cf * xe[8*s+j]);
                    af[s][j] = (__bf16)__builtin_amdgcn_sinf(a);
                }
        }
        __syncthreads();   // prefetch(fb+1) drained; all reads of buf fb&1 done
    }

    // ---- epilogue: transpose through wave-private LDS, then float4 stores ----
    // D layout: col = lane&31, row = (reg&3) + 8*(reg>>2) + 4*(lane>>5)
    float* lw = (float*)(smem + w * 16384);      // this wave's 16 KB
    #pragma unroll
    for (int t = 0; t < 4; ++t) {
        float bv = bias[t * 32 + hl];
        #pragma unroll
        for (int r = 0; r < 16; ++r) {
            int row = (r & 3) + 8 * (r >> 2) + 4 * h;
            lw[row * 128 + t * 32 + hl] = acc[t][r] + bv;
        }
    }
    // read back coalesced: inst i covers rows 2i+h, 16 floats per lane
    float4* of4 = (float4*)out;
    const float4* lw4 = (const float4*)lw;
    #pragma unroll
    for (int i = 0; i < 16; ++i) {
        float4 v = lw4[i * 64 + l];
        of4[(size_t)(m0 + 2 * i + h) * 32 + hl] = v;
    }
}

extern "C" void kernel_launch(void* const* d_in, const int* in_sizes, int n_in,
                              void* d_out, int out_size, void* d_ws, size_t ws_size,
                              hipStream_t stream) {
    const float* x      = (const float*)d_in[0];
    // d_in[1] = grid (values 1..8, folded into the per-block frequency)
    const float* base_w = (const float*)d_in[2];
    const float* scale  = (const float*)d_in[3];
    const float* coef   = (const float*)d_in[4];
    const float* conv_w = (const float*)d_in[5];
    const float* conv_b = (const float*)d_in[6];
    __bf16* Wp   = (__bf16*)d_ws;
    float*  bias = (float*)((char*)d_ws + BIAS_OFF);
    float*  out  = (float*)d_out;

    skan_prep<<<WP_CHUNKS / 256, 256, 0, stream>>>(base_w, scale, coef, conv_w, conv_b, Wp, bias);
    skan_main<<<NROWS / 128, 256, 0, stream>>>(x, Wp, bias, out);
}

// Round 3
// 113.339 us; speedup vs baseline: 1.0033x; 1.0033x over previous
//
#include <hip/hip_runtime.h>
#include <hip/hip_bf16.h>
#include <stdint.h>

#define IN_F   128
#define OUT_F  128
#define NUM_F  8
#define NROWS  (16*4096)

typedef __bf16  bf16x8  __attribute__((ext_vector_type(8)));
typedef float   f32x16  __attribute__((ext_vector_type(16)));

// W_perm: 9 feature-blocks x 8 k-steps x 4 n-tiles x 64 lanes x 8 bf16 = 294912 B
#define WP_CHUNKS (9*8*4*64)
#define WP_BYTES  (WP_CHUNKS*16)
#define BIAS_OFF  WP_BYTES

// ---------------- prep: build permuted bf16 weight + bias ----------------
__global__ __launch_bounds__(256) void skan_prep(
    const float* __restrict__ base_w,   // [OUT_F][IN_F]
    const float* __restrict__ scale,    // [OUT_F]
    const float* __restrict__ coef,     // [GROUPS][1][NUM_F]
    const float* __restrict__ conv_w,   // [NUM_F][OUT_F][IN_F]
    const float* __restrict__ conv_b,   // [NUM_F][OUT_F]
    __bf16* __restrict__ Wp, float* __restrict__ bias)
{
    int gid = blockIdx.x * 256 + threadIdx.x;        // 0..18431 chunk id
    int l  = gid & 63;
    int t  = (gid >> 6) & 3;
    int s  = (gid >> 8) & 7;
    int fb = gid >> 11;                              // 0..8
    int n  = t * 32 + (l & 31);
    int k0 = s * 16 + (l >> 5) * 8;
    __bf16* dst = Wp + (size_t)gid * 8;
    if (fb == 0) {
        #pragma unroll
        for (int j = 0; j < 8; ++j)
            dst[j] = (__bf16)base_w[n * IN_F + k0 + j];
    } else {
        int f = fb - 1;
        float sc = scale[n];
        #pragma unroll
        for (int j = 0; j < 8; ++j) {
            int k = k0 + j;
            float v = conv_w[((size_t)f * OUT_F + n) * IN_F + k]
                      * coef[(k >> 4) * NUM_F + f] * sc;
            dst[j] = (__bf16)v;
        }
    }
    if (gid < OUT_F) {
        float b = 0.f;
        #pragma unroll
        for (int f = 0; f < NUM_F; ++f) b += conv_b[f * OUT_F + gid];
        bias[gid] = b * scale[gid];
    }
}

// ---------------- main fused kernel ----------------
__device__ __forceinline__ void gld_lds16(const void* g, void* l) {
    __builtin_amdgcn_global_load_lds(
        (const __attribute__((address_space(1))) uint32_t*)g,
        (__attribute__((address_space(3))) uint32_t*)l, 16, 0, 0);
}

// stage 32 KB weight block fb into dstbuf, cooperative across 4 waves
#define STAGE(dstbuf, fbi)                                                    \
    {                                                                         \
        const char* _src = wpb + (size_t)(fbi) * 32768;                       \
        _Pragma("unroll")                                                     \
        for (int _r = 0; _r < 8; ++_r) {                                      \
            int _off = (_r * 4 + w) * 1024 + l * 16;                          \
            gld_lds16(_src + _off, (dstbuf) + _off);                          \
        }                                                                     \
    }

// sin-feature fb block: af generated per-s inline, 4 MFMAs per s
#define FBODY(curbuf, fbi)                                                    \
    {                                                                         \
        const bf16x8* _bp = (const bf16x8*)(curbuf);                          \
        float _cf = (float)(fbi) * 0.15915494309189535f;                      \
        _Pragma("unroll")                                                     \
        for (int _s = 0; _s < 8; ++_s) {                                      \
            bf16x8 _af;                                                       \
            _Pragma("unroll")                                                 \
            for (int _j = 0; _j < 8; ++_j) {                                  \
                float _a = __builtin_amdgcn_fractf(_cf * xe[8*_s+_j]);        \
                _af[_j] = (__bf16)__builtin_amdgcn_sinf(_a);                  \
            }                                                                 \
            _Pragma("unroll")                                                 \
            for (int _t = 0; _t < 4; ++_t) {                                  \
                bf16x8 _b = _bp[(_s * 4 + _t) * 64 + l];                      \
                acc[_t] = __builtin_amdgcn_mfma_f32_32x32x16_bf16(_af, _b, acc[_t], 0, 0, 0); \
            }                                                                 \
        }                                                                     \
    }

__global__ __launch_bounds__(256, 2) void skan_main(
    const float* __restrict__ x,        // [NROWS][IN_F]
    const __bf16* __restrict__ Wp,
    const float* __restrict__ bias,
    float* __restrict__ out)            // [NROWS][OUT_F]
{
    // two DISTINCT shared objects so alias analysis can separate
    // global_load_lds prefetch (one buf) from ds_read (other buf)
    __shared__ __align__(16) char bufA[32768];
    __shared__ __align__(16) char bufB[32768];

    const int tid = threadIdx.x;
    const int w   = tid >> 6;           // wave 0..3
    const int l   = tid & 63;
    const int hl  = l & 31;
    const int h   = l >> 5;
    const int m0  = blockIdx.x * 128 + w * 32;   // wave's row base
    const int m   = m0 + hl;                     // this lane's row (A operand)

    const char* wpb = (const char*)Wp;

    // ---- stage fb0 -> bufA, REDUNDANT per wave: no barrier needed before
    // fb0 (each wave's ds_reads depend only on its own vmcnt). Same-value
    // write races across waves are benign.
    #pragma unroll
    for (int i = 0; i < 32; ++i)
        gld_lds16(wpb + i * 1024 + l * 16, bufA + i * 1024 + l * 16);
    // ---- stage fb1 -> bufB, cooperative (consumed after first barrier)
    STAGE(bufB, 1);

    // ---- issue x loads (A-fragment order: col = s*16 + h*8 + j)
    const float4* x4p = (const float4*)x + (size_t)m * (IN_F / 4) + 2 * h;
    float xe[64];
    #pragma unroll
    for (int s = 0; s < 8; ++s) {
        float4 a = x4p[4 * s];
        float4 b = x4p[4 * s + 1];
        xe[8*s+0] = a.x; xe[8*s+1] = a.y; xe[8*s+2] = a.z; xe[8*s+3] = a.w;
        xe[8*s+4] = b.x; xe[8*s+5] = b.y; xe[8*s+6] = b.z; xe[8*s+7] = b.w;
    }

    f32x16 acc[4];
    #pragma unroll
    for (int t = 0; t < 4; ++t)
        #pragma unroll
        for (int r = 0; r < 16; ++r) acc[t][r] = 0.f;

    // ---- fb0: silu path, per-s inline (incremental vmcnt waits on x) ----
    {
        const bf16x8* bp = (const bf16x8*)bufA;
        #pragma unroll
        for (int s = 0; s < 8; ++s) {
            bf16x8 af;
            #pragma unroll
            for (int j = 0; j < 8; ++j) {
                float v = xe[8*s+j];
                af[j] = (__bf16)(v * __builtin_amdgcn_rcpf(1.0f + __expf(-v)));
            }
            #pragma unroll
            for (int t = 0; t < 4; ++t) {
                bf16x8 b = bp[(s * 4 + t) * 64 + l];
                acc[t] = __builtin_amdgcn_mfma_f32_32x32x16_bf16(af, b, acc[t], 0, 0, 0);
            }
        }
    }
    __syncthreads();   // bufB (fb1) staged by all waves

    // ---- fb1..8, software-pipelined over two distinct buffers ----
    #pragma unroll 1
    for (int p = 0; p < 4; ++p) {
        int fb = 2 * p + 1;
        STAGE(bufA, fb + 1);           // prefetch even block into bufA
        FBODY(bufB, fb);               // compute odd block from bufB
        __syncthreads();
        if (p < 3) STAGE(bufB, fb + 2);  // prefetch next odd into bufB
        FBODY(bufA, fb + 1);           // compute even block from bufA
        __syncthreads();
    }

    // ---- epilogue: barrier-free transpose through wave-private bufB region
    float*  lwf = (float*)(bufB + w * 8192);
    float4* lw4 = (float4*)lwf;
    float4* of4 = (float4*)out;
    #pragma unroll
    for (int p = 0; p < 2; ++p) {
        #pragma unroll
        for (int tt = 0; tt < 2; ++tt) {
            int t = 2 * p + tt;
            float bv = bias[t * 32 + hl];
            #pragma unroll
            for (int r = 0; r < 16; ++r) {
                int row = (r & 3) + 8 * (r >> 2) + 4 * h;   // D-layout row
                lwf[row * 64 + tt * 32 + hl] = acc[t][r] + bv;
            }
        }
        #pragma unroll
        for (int i = 0; i < 8; ++i) {
            float4 v = lw4[i * 64 + l];
            int row = i * 4 + (l >> 4);
            of4[(size_t)(m0 + row) * 32 + p * 16 + (l & 15)] = v;
        }
    }
}

extern "C" void kernel_launch(void* const* d_in, const int* in_sizes, int n_in,
                              void* d_out, int out_size, void* d_ws, size_t ws_size,
                              hipStream_t stream) {
    const float* x      = (const float*)d_in[0];
    // d_in[1] = grid (values 1..8, folded into the per-block frequency)
    const float* base_w = (const float*)d_in[2];
    const float* scale  = (const float*)d_in[3];
    const float* coef   = (const float*)d_in[4];
    const float* conv_w = (const float*)d_in[5];
    const float* conv_b = (const float*)d_in[6];
    __bf16* Wp   = (__bf16*)d_ws;
    float*  bias = (float*)((char*)d_ws + BIAS_OFF);
    float*  out  = (float*)d_out;

    skan_prep<<<WP_CHUNKS / 256, 256, 0, stream>>>(base_w, scale, coef, conv_w, conv_b, Wp, bias);
    skan_main<<<NROWS / 128, 256, 0, stream>>>(x, Wp, bias, out);
}